// Round 1
// 124.179 us; speedup vs baseline: 1.0099x; 1.0099x over previous
//
#include <hip/hip_runtime.h>

#define NUM_FRAME 300
#define LEN_FRAME 512
#define T_LEN     20000

typedef float floatx4 __attribute__((ext_vector_type(4)));
typedef int   int2a   __attribute__((ext_vector_type(2), aligned(4)));
typedef unsigned int uint32;
typedef long long i64;

// Per-pair LDS layout (BYTES), fp8 e4m3 samples (scaled x32):
//  A0 [0,752):       ext a8[x], x in [272,1024) at byte x-272.
//  A1 [756,1508):    identical copy at +756 (== 4 mod 8): rows il>=8 read it, so
//    their read2_b32 dwords are ODD -> 64 lanes cover all 32 banks, <=2 distinct
//    addresses/bank per read2 half = conflict-free (vs b64's even-only 4-addr 1.58x).
//  B [1512,...): 4 shift-copies b_s[p]=a8[(p+s)&511], s=0..3, stride 544 B;
//    read as read2_b32, uniform <=2 addr/bank (enumerated, R6-verified scheme).
#define A1_OFF  756
#define B_OFF   1512
#define B_STR   544
#define PAIR8   3696          // per (frame,ch), bytes (16-aligned)
#define SCR_OFF (4 * PAIR8)   // staggered float scratch for channel-mean

// Compile-time Hann*32 window table: w[n] = 32 * (0.5 - 0.5*cos(2*pi*n/512))
//                                         = 32 * sin^2(pi*n/512).
// Taylor sin on [0, pi/2] via quarter-wave symmetry; error ~1e-16 (irrelevant
// vs fp8 quantization). Lives in .rodata -> 1 global_load_dwordx4/thread,
// replacing 7 v_cos + window FMAs per thread per block.
struct alignas(16) WinTab {
    float w[512];
    constexpr WinTab() : w{} {
        for (int n = 0; n < 512; ++n) {
            int mm = (n <= 256) ? n : 512 - n;
            double x = 3.14159265358979323846 * (double)mm / 512.0;
            double t = x, s = x, x2 = x * x;
            for (int i = 1; i <= 10; ++i) { t *= -x2 / (double)((2 * i) * (2 * i + 1)); s += t; }
            w[n] = (float)(32.0 * s * s);
        }
    }
};
__device__ const WinTab wtab{};

__global__ __launch_bounds__(256, 8) void acorr_fp8(const float* __restrict__ in,
                                                    float* __restrict__ out) {
    __shared__ __align__(16) char lds8[4 * PAIR8 + 2112];   // 16896 B -> 8 blocks/CU

    const int tid = threadIdx.x;
    const int fj = tid >> 7;           // frame within block
    const int m  = tid & 127;          // owns samples x0..x0+3
    const int x0 = 4 * m;

    int   dreg[2];
    char* Pc[2];

    // ---------------- staging phase 1: load 4 owned samples, window (table),
    // ---------------- fp8(x32) pack, write A0/A1 ----------------
    {
        const int G  = blockIdx.x * 2 + fj;
        const int bc = (int)((unsigned)G / (unsigned)NUM_FRAME);
        const int fr = G - bc * NUM_FRAME;
        // exact: floor(fr*19488/299); fr=299 -> exactly 19488, no special case.
        // Matches the f64 linspace formula: frac parts are >= 1/299 from integers.
        const int start = (int)(((unsigned)fr * (unsigned)(T_LEN - LEN_FRAME))
                                / (unsigned)(NUM_FRAME - 1));
        const float2* src = (const float2*)(in + (size_t)2 * ((size_t)bc * T_LEN + start));

        const floatx4 wv = *(const floatx4*)&wtab.w[x0];   // 16B-aligned (x0 = 4m)
        const float2 v0 = src[x0], v1 = src[x0 + 1], v2 = src[x0 + 2], v3 = src[x0 + 3];

        #pragma unroll
        for (int c = 0; c < 2; ++c) {
            float f0 = (c ? v0.y : v0.x) * wv[0];
            float f1 = (c ? v1.y : v1.x) * wv[1];
            float f2 = (c ? v2.y : v2.x) * wv[2];
            float f3 = (c ? v3.y : v3.x) * wv[3];
            int d0 = __builtin_amdgcn_cvt_pk_fp8_f32(f0, f1, 0,  false);
            d0     = __builtin_amdgcn_cvt_pk_fp8_f32(f2, f3, d0, true);

            char* P = &lds8[(fj * 2 + c) * PAIR8];
            Pc[c]   = P;
            dreg[c] = d0;
            *(int*)(P + x0 + 240)          = d0;          // A0, ext [512,1024)
            *(int*)(P + A1_OFF + x0 + 240) = d0;          // A1 copy
            if (x0 >= 272) {
                *(int*)(P + x0 - 272)          = d0;      // A0, ext [272,512)
                *(int*)(P + A1_OFF + x0 - 272) = d0;
            }
        }
    }
    __syncthreads();

    // ---------------- staging phase 2: B shift-images ----------------
    // d1 (next dword of windowed fp8 samples) = neighbor thread's d0, re-read
    // from A0 at ext x = ((x0+4)&511)+512 -> byte ((x0+4)&511)+240.
    // alignbyte with s<=3 never uses byte 3 of d1 -> bit-identical to old path.
    {
        const int nbo = 240 + ((x0 + 4) & 511);
        #pragma unroll
        for (int c = 0; c < 2; ++c) {
            char* P = Pc[c];
            const int d0 = dreg[c];
            const int d1 = *(const int*)(P + nbo);
            #pragma unroll
            for (int s = 0; s < 4; ++s) {
                int dsv = (s == 0) ? d0
                        : (int)__builtin_amdgcn_alignbyte((uint32)d1, (uint32)d0, (uint32)s);
                *(int*)(P + B_OFF + B_STR * s + x0) = dsv;
                if (x0 < 16)                               // periodic tail
                    *(int*)(P + B_OFF + B_STR * s + x0 + 512) = dsv;
            }
        }
    }
    __syncthreads();

    // ---------------- MFMA main: wave w = pair w; 16 x (16x16x32 fp8_fp8), K=512 ----------------
    const int w    = tid >> 6;
    const int lane = tid & 63;
    const int il   = lane & 15;    // A row i / B col j
    const int q    = lane >> 4;

    const char* P  = &lds8[w * PAIR8];
    const char* aP = P + (240 + 8 * q - 16 * il) + ((il & 8) ? A1_OFF : 0);
    const char* bP = P + B_OFF + B_STR * (il & 3) + 8 * q + 4 * (il >> 2);

    floatx4 acc = {0.f, 0.f, 0.f, 0.f};
    #pragma unroll
    for (int u = 0; u < 16; ++u) {
        int2a av = *(const int2a*)(aP + 32 * u);          // ds_read2_b32, parity-staggered
        int2a bv = *(const int2a*)(bP + 32 * u);          // ds_read2_b32
        acc = __builtin_amdgcn_mfma_f32_16x16x32_fp8_fp8(
            __builtin_bit_cast(i64, av), __builtin_bit_cast(i64, bv), acc, 0, 0, 0);
    }

    // ---------------- epilogue: relu, 1/sqrt(acf0), channel mean, store ----------------
    // C/D layout: col j = lane&15, row i = 4q + reg -> lag = 16i + j.
    // acc = 1024 * acf (samples scaled x32).
    float n0  = __shfl(acc[0], 0, 64);
    float n0r = fmaxf(n0, 0.f);
    float inv = (n0r == 0.f) ? (1.0f / 1024.0f) : (rsqrtf(n0r) * (1.0f / 32.0f));
    float r0 = fmaxf(acc[0], 0.f) * inv;
    float r1 = fmaxf(acc[1], 0.f) * inv;
    float r2 = fmaxf(acc[2], 0.f) * inv;
    float r3 = fmaxf(acc[3], 0.f) * inv;

    // staggered scratch: stride 65 per q, 264 per frame -> <=2 lanes/bank per store
    float* scr = (float*)&lds8[SCR_OFF];
    const int f   = w >> 1;
    const int idx = f * 264 + q * 65 + il;
    if (w & 1) {                                          // ch1 -> scratch
        scr[idx +  0] = r0; scr[idx + 16] = r1;
        scr[idx + 32] = r2; scr[idx + 48] = r3;
    }
    __syncthreads();
    if (!(w & 1)) {                                       // ch0: mean + store
        const int G = blockIdx.x * 2 + f;
        float* ob = out + (size_t)G * 256 + q * 64 + il;
        ob[ 0] = 0.5f * (r0 + scr[idx +  0]);
        ob[16] = 0.5f * (r1 + scr[idx + 16]);
        ob[32] = 0.5f * (r2 + scr[idx + 32]);
        ob[48] = 0.5f * (r3 + scr[idx + 48]);
    }
}

extern "C" void kernel_launch(void* const* d_in, const int* in_sizes, int n_in,
                              void* d_out, int out_size, void* d_ws, size_t ws_size,
                              hipStream_t stream) {
    const float* in = (const float*)d_in[0];
    float* out = (float*)d_out;
    dim3 grid(30000);    // 60000 frames / 2 per block
    dim3 block(256);
    acorr_fp8<<<grid, block, 0, stream>>>(in, out);
}

// Round 2
// 120.788 us; speedup vs baseline: 1.0382x; 1.0281x over previous
//
#include <hip/hip_runtime.h>

#define NUM_FRAME 300
#define LEN_FRAME 512
#define T_LEN     20000

typedef float floatx4 __attribute__((ext_vector_type(4)));
typedef int   intx4   __attribute__((ext_vector_type(4)));
typedef int   intx8   __attribute__((ext_vector_type(8)));
typedef int   int2a   __attribute__((ext_vector_type(2), aligned(4)));
typedef int   int2w   __attribute__((ext_vector_type(2)));   // natural 8B align -> ds_write_b64
typedef unsigned int uint32;

// Per-pair LDS layout (BYTES), fp8 e4m3 samples (scaled x32):
//  A0 [0,752):  ext a8[x], x in [272,1024) at byte x-272.  Read as ds_read_b128
//    (K=128 frags: addr = 240 - 16*il + 32*q + 128*u (+16), 16B aligned; each
//    16-lane quarter covers a contiguous 256B span -> exactly 2 lanes/bank, free).
//  B [752,...): 4 shift-copies b_s[p]=a8[(p+s)&511], stride 560 (140 dw == 12 mod 32):
//    read2_b32 halves give bank = 12s + 8q + t + const -> enumerated exactly
//    2 lanes/bank, distinct addrs = free (m136: 2-way free). (544 would be 4-way.)
#define B_OFF  752
#define B_STR  560
#define PAIR8  2992           // 752 + 4*560, 16-aligned

// Compile-time Hann*32 window table: w[n] = 32 * sin^2(pi*n/512) (Taylor, ~1e-16).
struct alignas(16) WinTab {
    float w[512];
    constexpr WinTab() : w{} {
        for (int n = 0; n < 512; ++n) {
            int mm = (n <= 256) ? n : 512 - n;
            double x = 3.14159265358979323846 * (double)mm / 512.0;
            double t = x, s = x, x2 = x * x;
            for (int i = 1; i <= 10; ++i) { t *= -x2 / (double)((2 * i) * (2 * i + 1)); s += t; }
            w[n] = (float)(32.0 * s * s);
        }
    }
};
__device__ const WinTab wtab{};

__global__ __launch_bounds__(256, 6) void acorr_fp8(const float* __restrict__ in,
                                                    float* __restrict__ out) {
    __shared__ __align__(16) char lds8[8 * PAIR8];   // 23936 B -> 6 blocks/CU

    const int tid = threadIdx.x;
    const int fj  = tid >> 6;          // frame within block (wave fj computes frame fj)
    const int m   = tid & 63;          // owns samples x0..x0+7
    const int x0  = 8 * m;

    // ---------------- staging: window (table) -> fp8(x32) -> A0 + 4 B shift-images ----------------
    {
        const int G  = blockIdx.x * 4 + fj;
        const int bc = (int)((unsigned)G / (unsigned)NUM_FRAME);
        const int fr = G - bc * NUM_FRAME;
        // exact: floor(fr*19488/299); fr=299 -> exactly 19488 (matches f64 linspace).
        const int start = (int)(((unsigned)fr * (unsigned)(T_LEN - LEN_FRAME))
                                / (unsigned)(NUM_FRAME - 1));
        const float2* src = (const float2*)(in + (size_t)2 * ((size_t)bc * T_LEN + start));

        const int cn = (x0 + 8) & 511;                 // circular context base (3 bytes used)

        const float2 v0 = src[x0],     v1 = src[x0 + 1], v2 = src[x0 + 2], v3 = src[x0 + 3];
        const float2 v4 = src[x0 + 4], v5 = src[x0 + 5], v6 = src[x0 + 6], v7 = src[x0 + 7];
        const float2 c0 = src[cn],     c1 = src[cn + 1], c2 = src[cn + 2], c3 = src[cn + 3];

        const floatx4 wva = *(const floatx4*)&wtab.w[x0];
        const floatx4 wvb = *(const floatx4*)&wtab.w[x0 + 4];
        const floatx4 wvc = *(const floatx4*)&wtab.w[cn];

        #pragma unroll
        for (int c = 0; c < 2; ++c) {
            float f0 = (c ? v0.y : v0.x) * wva[0];
            float f1 = (c ? v1.y : v1.x) * wva[1];
            float f2 = (c ? v2.y : v2.x) * wva[2];
            float f3 = (c ? v3.y : v3.x) * wva[3];
            float f4 = (c ? v4.y : v4.x) * wvb[0];
            float f5 = (c ? v5.y : v5.x) * wvb[1];
            float f6 = (c ? v6.y : v6.x) * wvb[2];
            float f7 = (c ? v7.y : v7.x) * wvb[3];
            float g0 = (c ? c0.y : c0.x) * wvc[0];
            float g1 = (c ? c1.y : c1.x) * wvc[1];
            float g2 = (c ? c2.y : c2.x) * wvc[2];
            float g3 = (c ? c3.y : c3.x) * wvc[3];

            int d0 = __builtin_amdgcn_cvt_pk_fp8_f32(f0, f1, 0,  false);
            d0     = __builtin_amdgcn_cvt_pk_fp8_f32(f2, f3, d0, true);
            int d1 = __builtin_amdgcn_cvt_pk_fp8_f32(f4, f5, 0,  false);
            d1     = __builtin_amdgcn_cvt_pk_fp8_f32(f6, f7, d1, true);
            int d2 = __builtin_amdgcn_cvt_pk_fp8_f32(g0, g1, 0,  false);
            d2     = __builtin_amdgcn_cvt_pk_fp8_f32(g2, g3, d2, true);

            char* P = &lds8[(fj * 2 + c) * PAIR8];
            *(int2w*)(P + 240 + x0) = (int2w){d0, d1};            // A0 ext [512,1024)
            if (x0 >= 272)
                *(int2w*)(P + x0 - 272) = (int2w){d0, d1};        // A0 ext [272,512)
            #pragma unroll
            for (int s = 0; s < 4; ++s) {
                int e0 = (s == 0) ? d0
                       : (int)__builtin_amdgcn_alignbyte((uint32)d1, (uint32)d0, (uint32)s);
                int e1 = (s == 0) ? d1
                       : (int)__builtin_amdgcn_alignbyte((uint32)d2, (uint32)d1, (uint32)s);
                *(int2w*)(P + B_OFF + B_STR * s + x0) = (int2w){e0, e1};
                if (x0 < 16)                                       // periodic tail [512,528)
                    *(int2w*)(P + B_OFF + B_STR * s + x0 + 512) = (int2w){e0, e1};
            }
        }
    }
    __syncthreads();

    // ---------------- MFMA main: wave = frame; both channels; 4 x (16x16x128 f8f6f4 fp8) ----------------
    const int lane = tid & 63;
    const int il   = lane & 15;    // A row i / B col j
    const int q    = lane >> 4;    // k-block

    const char* P0 = &lds8[(fj * 2) * PAIR8];                     // ch0; ch1 at +PAIR8
    const char* aP = P0 + (240 - 16 * il + 32 * q);
    const char* bP = P0 + B_OFF + B_STR * (il & 3) + 4 * (il >> 2) + 32 * q;

    floatx4 acc0 = {0.f, 0.f, 0.f, 0.f};
    floatx4 acc1 = {0.f, 0.f, 0.f, 0.f};
    #pragma unroll
    for (int u = 0; u < 4; ++u) {
        const int o = 128 * u;
        // ch0
        {
            intx4 al = *(const intx4*)(aP + o);                   // ds_read_b128
            intx4 ah = *(const intx4*)(aP + o + 16);
            int2a b0 = *(const int2a*)(bP + o);                   // ds_read2_b32 x4
            int2a b1 = *(const int2a*)(bP + o + 8);
            int2a b2 = *(const int2a*)(bP + o + 16);
            int2a b3 = *(const int2a*)(bP + o + 24);
            intx8 a = {al.x, al.y, al.z, al.w, ah.x, ah.y, ah.z, ah.w};
            intx8 b = {b0.x, b0.y, b1.x, b1.y, b2.x, b2.y, b3.x, b3.y};
            acc0 = __builtin_amdgcn_mfma_scale_f32_16x16x128_f8f6f4(
                a, b, acc0, 0, 0, 0, 0x7F7F7F7F, 0, 0x7F7F7F7F);  // scales = 1.0 (e8m0 127)
        }
        // ch1
        {
            intx4 al = *(const intx4*)(aP + PAIR8 + o);
            intx4 ah = *(const intx4*)(aP + PAIR8 + o + 16);
            int2a b0 = *(const int2a*)(bP + PAIR8 + o);
            int2a b1 = *(const int2a*)(bP + PAIR8 + o + 8);
            int2a b2 = *(const int2a*)(bP + PAIR8 + o + 16);
            int2a b3 = *(const int2a*)(bP + PAIR8 + o + 24);
            intx8 a = {al.x, al.y, al.z, al.w, ah.x, ah.y, ah.z, ah.w};
            intx8 b = {b0.x, b0.y, b1.x, b1.y, b2.x, b2.y, b3.x, b3.y};
            acc1 = __builtin_amdgcn_mfma_scale_f32_16x16x128_f8f6f4(
                a, b, acc1, 0, 0, 0, 0x7F7F7F7F, 0, 0x7F7F7F7F);
        }
    }

    // ---------------- epilogue: per-channel relu + 1/sqrt(acf0), in-register mean, store ----------------
    // C/D layout: col j = lane&15, row i = 4q + reg -> lag = 16i + j. acc = 1024*acf.
    // acf[0] lives in lane 0 reg 0 -> readfirstlane (SALU broadcast, no LDS).
    float n00 = __int_as_float(__builtin_amdgcn_readfirstlane(__float_as_int(acc0[0])));
    float n01 = __int_as_float(__builtin_amdgcn_readfirstlane(__float_as_int(acc1[0])));
    float n0r0 = fmaxf(n00, 0.f);
    float n0r1 = fmaxf(n01, 0.f);
    float inv0 = (n0r0 == 0.f) ? (1.0f / 1024.0f) : (rsqrtf(n0r0) * (1.0f / 32.0f));
    float inv1 = (n0r1 == 0.f) ? (1.0f / 1024.0f) : (rsqrtf(n0r1) * (1.0f / 32.0f));

    const int G = blockIdx.x * 4 + fj;
    float* ob = out + (size_t)G * 256 + q * 64 + il;
    ob[ 0] = 0.5f * (fmaxf(acc0[0], 0.f) * inv0 + fmaxf(acc1[0], 0.f) * inv1);
    ob[16] = 0.5f * (fmaxf(acc0[1], 0.f) * inv0 + fmaxf(acc1[1], 0.f) * inv1);
    ob[32] = 0.5f * (fmaxf(acc0[2], 0.f) * inv0 + fmaxf(acc1[2], 0.f) * inv1);
    ob[48] = 0.5f * (fmaxf(acc0[3], 0.f) * inv0 + fmaxf(acc1[3], 0.f) * inv1);
}

extern "C" void kernel_launch(void* const* d_in, const int* in_sizes, int n_in,
                              void* d_out, int out_size, void* d_ws, size_t ws_size,
                              hipStream_t stream) {
    const float* in = (const float*)d_in[0];
    float* out = (float*)d_out;
    dim3 grid(15000);    // 60000 frames / 4 per block (1 wave per frame, both channels)
    dim3 block(256);
    acorr_fp8<<<grid, block, 0, stream>>>(in, out);
}